// Round 1
// baseline (34.672 us; speedup 1.0000x reference)
//
#include <hip/hip_runtime.h>
#include <math.h>

// DSS "softmax" kernel: K[c,h,l] = Re( sum_n Wc[c,h,n] * exp(z[h,n]*(l - loff)) )
// Strategy: per-(h,n) coefficients in f64 (once per block, 64-lane preamble -> LDS),
// then f32 main loop with HW transcendentals (v_exp_f32 / v_sin_f32 / v_cos_f32)
// and FMA-compensated phase for accuracy at large l.

#if __has_builtin(__builtin_amdgcn_sinf)
__device__ inline float vsin_rev(float x) { return __builtin_amdgcn_sinf(x); }   // sin(2*pi*x)
__device__ inline float vcos_rev(float x) { return __builtin_amdgcn_cosf(x); }   // cos(2*pi*x)
#else
__device__ inline float vsin_rev(float x) { return __sinf(x * 6.28318530717958647692f); }
__device__ inline float vcos_rev(float x) { return __cosf(x * 6.28318530717958647692f); }
#endif

__global__ __launch_bounds__(256) void dss_kernel(
    const float* __restrict__ Lambda,   // [N,2]
    const float* __restrict__ log_dt,   // [H,2]
    const float* __restrict__ W,        // [C,H,N,2]
    float* __restrict__ out,            // [C,H,L]
    int H, int N, int L, int C, int chunks)
{
    __shared__ float4 pA[64];   // wr, wi, er (= zr*log2e), loff
    __shared__ float2 pB[64];   // ph_hi, ph_lo  (zi / 2pi, hi/lo split)

    const int h     = blockIdx.x / chunks;
    const int chunk = blockIdx.x % chunks;
    const int c     = blockIdx.y;
    const int tid   = threadIdx.x;

    // ---- per-(h,n) coefficient preamble (f64, 64 lanes) ----
    if (tid < N) {
        const int n = tid;
        double dt0 = exp((double)log_dt[h*2 + 0]);
        double dt1 = exp((double)log_dt[h*2 + 1]);
        double lre = (double)Lambda[n*2 + 0];
        double lim = (double)Lambda[n*2 + 1];
        double zr = dt0 * lre;
        double zi = dt1 * lim;
        bool gt0 = (lre > 0.0);
        double sgn = gt0 ? -1.0 : 1.0;
        double dnr = sgn * zr, dni = sgn * zi;
        // num = exp(dn) - 1
        double ednr  = exp(dnr);
        double num_re = ednr * cos(dni) - 1.0;
        double num_im = ednr * sin(dni);
        // den = exp(L*dn) - 1
        double Ld = (double)L;
        double eLr = exp(Ld * dnr);
        double den_re = eLr * cos(Ld * dni) - 1.0;
        double den_im = eLr * sin(Ld * dni);
        // x = den * Lam ; recip = conj(x)/(|x|^2 + eps)
        double x_re = den_re * lre - den_im * lim;
        double x_im = den_re * lim + den_im * lre;
        double inv  = 1.0 / (x_re*x_re + x_im*x_im + 1e-7);
        double r_re =  x_re * inv;
        double r_im = -x_im * inv;
        // m = num * recip
        double m_re = num_re * r_re - num_im * r_im;
        double m_im = num_re * r_im + num_im * r_re;
        // Wc = (W0 + i*W1) * m
        double w0 = (double)W[((size_t)(c*H + h)*N + n)*2 + 0];
        double w1 = (double)W[((size_t)(c*H + h)*N + n)*2 + 1];
        double wr = w0 * m_re - w1 * m_im;
        double wi = w0 * m_im + w1 * m_re;
        double loff = gt0 ? (double)(L - 1) : 0.0;

        const double LOG2E  = 1.4426950408889634074;
        const double INV2PI = 0.15915494309189533577;
        double er = zr * LOG2E;
        double ph = zi * INV2PI;
        float ph_hi = (float)ph;
        float ph_lo = (float)(ph - (double)ph_hi);

        pA[n] = make_float4((float)wr, (float)wi, (float)er, (float)loff);
        pB[n] = make_float2(ph_hi, ph_lo);
    }
    __syncthreads();

    // ---- main loop: 4 l-values per thread, coalesced ----
    const int lchunk = L / chunks;           // 1024
    const int lbase  = chunk * lchunk;

    float acc[4];
    float lf[4];
    #pragma unroll
    for (int k = 0; k < 4; ++k) {
        acc[k] = 0.0f;
        lf[k]  = (float)(lbase + tid + k * 256);
    }

    for (int n = 0; n < N; ++n) {
        const float4 a = pA[n];              // broadcast read: no bank conflict
        const float2 b = pB[n];
        #pragma unroll
        for (int k = 0; k < 4; ++k) {
            float x  = lf[k] - a.w;                       // l - loff
            float e  = __builtin_amdgcn_exp2f(a.z * x);   // exp(zr*x)
            // phase = (ph_hi + ph_lo)*x, FMA-compensated, reduced mod 1 (revolutions)
            float p  = b.x * x;
            float e1 = fmaf(b.x, x, -p);                  // exact product error
            float f  = (p - floorf(p)) + fmaf(b.y, x, e1);
            float s  = vsin_rev(f);
            float co = vcos_rev(f);
            float t  = a.x * co;
            t        = fmaf(-a.y, s, t);                  // Re(Wc * cis)
            acc[k]   = fmaf(e, t, acc[k]);
        }
    }

    float* o = out + ((size_t)c * H + h) * (size_t)L + lbase + tid;
    #pragma unroll
    for (int k = 0; k < 4; ++k) o[k * 256] = acc[k];
}

extern "C" void kernel_launch(void* const* d_in, const int* in_sizes, int n_in,
                              void* d_out, int out_size, void* d_ws, size_t ws_size,
                              hipStream_t stream) {
    // d_in[0] = L (scalar int, unused on device; derived from out_size)
    const float* Lambda = (const float*)d_in[1];   // [N,2]
    const float* log_dt = (const float*)d_in[2];   // [H,2]
    const float* W      = (const float*)d_in[3];   // [C,H,N,2]
    float* out = (float*)d_out;

    const int N = in_sizes[1] / 2;                 // 64
    const int H = in_sizes[2] / 2;                 // 128
    const int C = in_sizes[3] / (2 * H * N);       // 1
    const int L = out_size / (C * H);              // 8192

    const int chunks = L / 1024;                   // 8 -> 1024 blocks, 4 l's/thread
    dim3 grid(H * chunks, C);
    dss_kernel<<<grid, 256, 0, stream>>>(Lambda, log_dt, W, out, H, N, L, C, chunks);
}

// Round 2
// 20.499 us; speedup vs baseline: 1.6914x; 1.6914x over previous
//
#include <hip/hip_runtime.h>
#include <math.h>

// DSS "softmax" kernel: K[c,h,l] = Re( sum_n Wc[c,h,n] * exp(z[h,n]*(l - loff)) )
// Round 2: geometric recurrence along l. Each thread owns K=8 l-values at
// stride 256. State T = Wc*exp(z*x) folded; per element: acc += Re(T),
// T *= R where R = exp(z*256) (f64-exact per-n constant). Trans ops only
// once per (n, thread) -> ~8x fewer v_sin/v_cos/v_exp.

#if __has_builtin(__builtin_amdgcn_sinf)
__device__ inline float vsin_rev(float x) { return __builtin_amdgcn_sinf(x); }   // sin(2*pi*x)
__device__ inline float vcos_rev(float x) { return __builtin_amdgcn_cosf(x); }   // cos(2*pi*x)
#else
__device__ inline float vsin_rev(float x) { return __sinf(x * 6.28318530717958647692f); }
__device__ inline float vcos_rev(float x) { return __cosf(x * 6.28318530717958647692f); }
#endif

#define KPT 8          // l-values per thread
#define TPB 256        // threads per block

__global__ __launch_bounds__(TPB) void dss_kernel(
    const float* __restrict__ Lambda,   // [N,2]
    const float* __restrict__ log_dt,   // [H,2]
    const float* __restrict__ W,        // [C,H,N,2]
    float* __restrict__ out,            // [C,H,L]
    int H, int N, int L, int C, int chunks)
{
    __shared__ float4 pA[64];   // wr, wi, er (= zr*log2e), loff
    __shared__ float4 pB[64];   // ph_hi, ph_lo (zi/2pi split), Rr, Ri

    const int h     = blockIdx.x / chunks;
    const int chunk = blockIdx.x % chunks;
    const int c     = blockIdx.y;
    const int tid   = threadIdx.x;

    // ---- per-(h,n) coefficient preamble (f64, 64 lanes) ----
    if (tid < N) {
        const int n = tid;
        double dt0 = exp((double)log_dt[h*2 + 0]);
        double dt1 = exp((double)log_dt[h*2 + 1]);
        double lre = (double)Lambda[n*2 + 0];
        double lim = (double)Lambda[n*2 + 1];
        double zr = dt0 * lre;
        double zi = dt1 * lim;
        bool gt0 = (lre > 0.0);
        double sgn = gt0 ? -1.0 : 1.0;
        double dnr = sgn * zr, dni = sgn * zi;
        // num = exp(dn) - 1
        double ednr  = exp(dnr);
        double num_re = ednr * cos(dni) - 1.0;
        double num_im = ednr * sin(dni);
        // den = exp(L*dn) - 1
        double Ld = (double)L;
        double eLr = exp(Ld * dnr);
        double den_re = eLr * cos(Ld * dni) - 1.0;
        double den_im = eLr * sin(Ld * dni);
        // x = den * Lam ; recip = conj(x)/(|x|^2 + eps)
        double x_re = den_re * lre - den_im * lim;
        double x_im = den_re * lim + den_im * lre;
        double inv  = 1.0 / (x_re*x_re + x_im*x_im + 1e-7);
        double r_re =  x_re * inv;
        double r_im = -x_im * inv;
        // m = num * recip
        double m_re = num_re * r_re - num_im * r_im;
        double m_im = num_re * r_im + num_im * r_re;
        // Wc = (W0 + i*W1) * m
        double w0 = (double)W[((size_t)(c*H + h)*N + n)*2 + 0];
        double w1 = (double)W[((size_t)(c*H + h)*N + n)*2 + 1];
        double wr = w0 * m_re - w1 * m_im;
        double wi = w0 * m_im + w1 * m_re;
        double loff = gt0 ? (double)(L - 1) : 0.0;

        const double LOG2E  = 1.4426950408889634074;
        const double INV2PI = 0.15915494309189533577;
        double er = zr * LOG2E;
        double ph = zi * INV2PI;
        float ph_hi = (float)ph;
        float ph_lo = (float)(ph - (double)ph_hi);

        // R = exp(z * TPB)  (step between this thread's consecutive l's)
        double Sd  = (double)TPB;
        double mag = exp(zr * Sd);
        double ang = zi * Sd;                 // radians, f64 range reduction exact enough
        float Rr = (float)(mag * cos(ang));
        float Ri = (float)(mag * sin(ang));

        pA[n] = make_float4((float)wr, (float)wi, (float)er, (float)loff);
        pB[n] = make_float4(ph_hi, ph_lo, Rr, Ri);
    }
    __syncthreads();

    // ---- main loop: KPT l-values per thread via complex recurrence ----
    const int lchunk = KPT * TPB;            // elements per block
    const int lbase  = chunk * lchunk;
    const float x0f  = (float)(lbase + tid);

    float acc[KPT];
    #pragma unroll
    for (int k = 0; k < KPT; ++k) acc[k] = 0.0f;

    for (int n = 0; n < N; ++n) {
        const float4 a = pA[n];              // broadcast read: no bank conflict
        const float4 b = pB[n];
        float x  = x0f - a.w;                          // l - loff
        float e  = __builtin_amdgcn_exp2f(a.z * x);    // |exp(zr*x)|
        // phase = (ph_hi + ph_lo)*x, FMA-compensated, mod 1 (revolutions)
        float p  = b.x * x;
        float e1 = fmaf(b.x, x, -p);
        float f  = (p - floorf(p)) + fmaf(b.y, x, e1);
        float s  = vsin_rev(f);
        float co = vcos_rev(f);
        // T = Wc * e * cis(f)
        float tr = fmaf(a.x, co, -(a.y * s));
        float ti = fmaf(a.x, s,   a.y * co);
        float Tr = e * tr;
        float Ti = e * ti;
        #pragma unroll
        for (int k = 0; k < KPT; ++k) {
            acc[k] += Tr;
            if (k < KPT - 1) {
                float t = fmaf(Tr, b.z, -(Ti * b.w));  // Tr*Rr - Ti*Ri
                Ti      = fmaf(Tr, b.w,   Ti * b.z);   // Tr*Ri + Ti*Rr
                Tr      = t;
            }
        }
    }

    float* o = out + ((size_t)c * H + h) * (size_t)L + lbase + tid;
    #pragma unroll
    for (int k = 0; k < KPT; ++k) {
        int l = lbase + tid + k * TPB;
        if (l < L) o[k * TPB] = acc[k];
    }
}

extern "C" void kernel_launch(void* const* d_in, const int* in_sizes, int n_in,
                              void* d_out, int out_size, void* d_ws, size_t ws_size,
                              hipStream_t stream) {
    // d_in[0] = L (scalar, unused on device; derived from out_size)
    const float* Lambda = (const float*)d_in[1];   // [N,2]
    const float* log_dt = (const float*)d_in[2];   // [H,2]
    const float* W      = (const float*)d_in[3];   // [C,H,N,2]
    float* out = (float*)d_out;

    const int N = in_sizes[1] / 2;                 // 64
    const int H = in_sizes[2] / 2;                 // 128
    const int C = in_sizes[3] / (2 * H * N);       // 1
    const int L = out_size / (C * H);              // 8192

    const int per_block = KPT * TPB;               // 2048
    const int chunks = (L + per_block - 1) / per_block;   // 4
    dim3 grid(H * chunks, C);
    dss_kernel<<<grid, TPB, 0, stream>>>(Lambda, log_dt, W, out, H, N, L, C, chunks);
}

// Round 3
// 17.172 us; speedup vs baseline: 2.0191x; 1.1938x over previous
//
#include <hip/hip_runtime.h>
#include <math.h>

// DSS "softmax" kernel: K[c,h,l] = Re( sum_n Wc[c,h,n] * exp(z[h,n]*(l - loff)) )
// Round 3: Chebyshev 3-term recurrence along l (x_{k+1} = 2Re(R) x_k - |R|^2 x_{k-1},
// R = exp(z*256)), n-unrolled x4 into 2 packed float2 chains (v_pk_fma_f32),
// separate accumulator banks. Trans ops once per (n, thread).

#if __has_builtin(__builtin_amdgcn_sinf)
__device__ inline float vsin_rev(float x) { return __builtin_amdgcn_sinf(x); }   // sin(2*pi*x)
__device__ inline float vcos_rev(float x) { return __builtin_amdgcn_cosf(x); }   // cos(2*pi*x)
#else
__device__ inline float vsin_rev(float x) { return __sinf(x * 6.28318530717958647692f); }
__device__ inline float vcos_rev(float x) { return __cosf(x * 6.28318530717958647692f); }
#endif

typedef float v2f __attribute__((ext_vector_type(2)));

#define KPT 8          // l-values per thread
#define TPB 256        // threads per block

__global__ __launch_bounds__(TPB) void dss_kernel(
    const float* __restrict__ Lambda,   // [N,2]
    const float* __restrict__ log_dt,   // [H,2]
    const float* __restrict__ W,        // [C,H,N,2]
    float* __restrict__ out,            // [C,H,L]
    int H, int N, int L, int C, int chunks)
{
    __shared__ float4 pA[64];   // wr, wi, er (= zr*log2e), loff
    __shared__ float4 pB[64];   // ph_hi, ph_lo (zi/2pi split), c1 (=2*Rr), c2 (=-|R|^2)
    __shared__ float2 pC[64];   // Rr, Ri

    const int h     = blockIdx.x / chunks;
    const int chunk = blockIdx.x % chunks;
    const int c     = blockIdx.y;
    const int tid   = threadIdx.x;

    // ---- per-(h,n) coefficient preamble (f64, 64 lanes) ----
    if (tid < N) {
        const int n = tid;
        double dt0 = exp((double)log_dt[h*2 + 0]);
        double dt1 = exp((double)log_dt[h*2 + 1]);
        double lre = (double)Lambda[n*2 + 0];
        double lim = (double)Lambda[n*2 + 1];
        double zr = dt0 * lre;
        double zi = dt1 * lim;
        bool gt0 = (lre > 0.0);
        double sgn = gt0 ? -1.0 : 1.0;
        double dnr = sgn * zr, dni = sgn * zi;
        // num = exp(dn) - 1
        double ednr  = exp(dnr);
        double num_re = ednr * cos(dni) - 1.0;
        double num_im = ednr * sin(dni);
        // den = exp(L*dn) - 1
        double Ld = (double)L;
        double eLr = exp(Ld * dnr);
        double den_re = eLr * cos(Ld * dni) - 1.0;
        double den_im = eLr * sin(Ld * dni);
        // x = den * Lam ; recip = conj(x)/(|x|^2 + eps)
        double x_re = den_re * lre - den_im * lim;
        double x_im = den_re * lim + den_im * lre;
        double inv  = 1.0 / (x_re*x_re + x_im*x_im + 1e-7);
        double r_re =  x_re * inv;
        double r_im = -x_im * inv;
        // m = num * recip
        double m_re = num_re * r_re - num_im * r_im;
        double m_im = num_re * r_im + num_im * r_re;
        // Wc = (W0 + i*W1) * m
        double w0 = (double)W[((size_t)(c*H + h)*N + n)*2 + 0];
        double w1 = (double)W[((size_t)(c*H + h)*N + n)*2 + 1];
        double wr = w0 * m_re - w1 * m_im;
        double wi = w0 * m_im + w1 * m_re;
        double loff = gt0 ? (double)(L - 1) : 0.0;

        const double LOG2E  = 1.4426950408889634074;
        const double INV2PI = 0.15915494309189533577;
        double er = zr * LOG2E;
        double ph = zi * INV2PI;
        float ph_hi = (float)ph;
        float ph_lo = (float)(ph - (double)ph_hi);

        // R = exp(z*TPB): step between this thread's consecutive l's
        double Sd  = (double)TPB;
        double mag = exp(zr * Sd);
        double ang = zi * Sd;
        double Rr  = mag * cos(ang);
        double Ri  = mag * sin(ang);
        double c1  = 2.0 * Rr;           // Chebyshev coefficients
        double c2  = -(mag * mag);

        pA[n] = make_float4((float)wr, (float)wi, (float)er, (float)loff);
        pB[n] = make_float4(ph_hi, ph_lo, (float)c1, (float)c2);
        pC[n] = make_float2((float)Rr, (float)Ri);
    }
    __syncthreads();

    // ---- main loop: KPT l-values per thread, 4 n-chains (2 packed pairs) ----
    const int lchunk = KPT * TPB;
    const int lbase  = chunk * lchunk;
    const float x0f  = (float)(lbase + tid);

    v2f acc2a[KPT], acc2b[KPT];
    #pragma unroll
    for (int k = 0; k < KPT; ++k) { acc2a[k] = (v2f)(0.0f); acc2b[k] = (v2f)(0.0f); }

    for (int n = 0; n < N; n += 4) {
        float4 A[4], B[4]; float2 Rv[4];
        #pragma unroll
        for (int j = 0; j < 4; ++j) { A[j] = pA[n+j]; B[j] = pB[n+j]; Rv[j] = pC[n+j]; }

        float X0[4], X1[4];
        #pragma unroll
        for (int j = 0; j < 4; ++j) {
            const float4 a = A[j]; const float4 b = B[j]; const float2 r = Rv[j];
            float x  = x0f - a.w;                          // l - loff
            float e  = __builtin_amdgcn_exp2f(a.z * x);    // |exp(zr*x)|
            float p  = b.x * x;                            // phase (rev), FMA-compensated
            float e1 = fmaf(b.x, x, -p);
            float f  = (p - floorf(p)) + fmaf(b.y, x, e1);
            float s  = vsin_rev(f);
            float co = vcos_rev(f);
            float tr = fmaf(a.x, co, -(a.y * s));
            float ti = fmaf(a.x, s,   a.y * co);
            float Tr = e * tr;                             // x_0 = Re(T)
            float Ti = e * ti;
            X0[j] = Tr;
            X1[j] = fmaf(Tr, r.x, -(Ti * r.y));            // x_1 = Re(T*R)
        }

        v2f x0a = {X0[0], X0[1]}, x1a = {X1[0], X1[1]};
        v2f x0b = {X0[2], X0[3]}, x1b = {X1[2], X1[3]};
        v2f c1a = {B[0].z, B[1].z}, c2a = {B[0].w, B[1].w};
        v2f c1b = {B[2].z, B[3].z}, c2b = {B[2].w, B[3].w};

        acc2a[0] += x0a; acc2a[1] += x1a;
        acc2b[0] += x0b; acc2b[1] += x1b;
        #pragma unroll
        for (int k = 2; k < KPT; ++k) {
            v2f ta = c2a * x0a;
            v2f xa = __builtin_elementwise_fma(c1a, x1a, ta);
            acc2a[k] += xa; x0a = x1a; x1a = xa;
            v2f tb = c2b * x0b;
            v2f xb = __builtin_elementwise_fma(c1b, x1b, tb);
            acc2b[k] += xb; x0b = x1b; x1b = xb;
        }
    }

    float* o = out + ((size_t)c * H + h) * (size_t)L + lbase + tid;
    #pragma unroll
    for (int k = 0; k < KPT; ++k) {
        int l = lbase + tid + k * TPB;
        if (l < L) o[k * TPB] = acc2a[k].x + acc2a[k].y + acc2b[k].x + acc2b[k].y;
    }
}

extern "C" void kernel_launch(void* const* d_in, const int* in_sizes, int n_in,
                              void* d_out, int out_size, void* d_ws, size_t ws_size,
                              hipStream_t stream) {
    // d_in[0] = L (scalar, unused on device; derived from out_size)
    const float* Lambda = (const float*)d_in[1];   // [N,2]
    const float* log_dt = (const float*)d_in[2];   // [H,2]
    const float* W      = (const float*)d_in[3];   // [C,H,N,2]
    float* out = (float*)d_out;

    const int N = in_sizes[1] / 2;                 // 64
    const int H = in_sizes[2] / 2;                 // 128
    const int C = in_sizes[3] / (2 * H * N);       // 1
    const int L = out_size / (C * H);              // 8192

    const int per_block = KPT * TPB;               // 2048
    const int chunks = (L + per_block - 1) / per_block;   // 4
    dim3 grid(H * chunks, C);
    dss_kernel<<<grid, TPB, 0, stream>>>(Lambda, log_dt, W, out, H, N, L, C, chunks);
}